// Round 1
// baseline (185.272 us; speedup 1.0000x reference)
//
#include <hip/hip_runtime.h>

#define NN 512
#define NE 16384
#define NF 64

// ---------------------------------------------------------------------------
// K2: scatter edge ids into dense [N][N] tables (forward and transposed).
// Tables pre-filled with -1 via hipMemsetAsync(0xFF).
// ---------------------------------------------------------------------------
__global__ void k_scatter(const int* __restrict__ ei,
                          int* __restrict__ eid, int* __restrict__ eidT) {
  int e = blockIdx.x * 256 + threadIdx.x;
  if (e < NE) {
    int i = ei[e];
    int k = ei[NE + e];
    eid[i * NN + k] = e;
    eidT[k * NN + i] = e;
  }
}

__device__ inline float dot4(float4 a, float4 b, float acc) {
  acc = fmaf(a.x, b.x, acc);
  acc = fmaf(a.y, b.y, acc);
  acc = fmaf(a.z, b.z, acc);
  acc = fmaf(a.w, b.w, acc);
  return acc;
}

// ---------------------------------------------------------------------------
// K3: X = C @ W_L1^T, Y = C @ W_L2^T.  [E,64] @ [64,64]^T.
// One wave per 16 edges; lane = output column o. Each lane caches its W rows
// (64 floats x 2 matrices = 32 float4) in VGPRs; C row loads are wave-uniform
// (L1 broadcast). Stores coalesced.
// ---------------------------------------------------------------------------
__global__ __launch_bounds__(256) void k_xy(const float* __restrict__ C,
                                            const float* __restrict__ W1,
                                            const float* __restrict__ W2,
                                            float* __restrict__ X,
                                            float* __restrict__ Y) {
  int lane = threadIdx.x & 63;
  int wv = (blockIdx.x * 256 + threadIdx.x) >> 6;  // 0..1023
  const float4* W14 = (const float4*)W1;           // [64][16]
  const float4* W24 = (const float4*)W2;
  float4 w1r[16], w2r[16];
#pragma unroll
  for (int q = 0; q < 16; q++) {
    w1r[q] = W14[lane * 16 + q];
    w2r[q] = W24[lane * 16 + q];
  }
  for (int m = 0; m < 16; m++) {
    int e = wv * 16 + m;
    const float4* c4 = (const float4*)(C + (size_t)e * 64);
    float ax = 0.f, ay = 0.f;
#pragma unroll
    for (int q = 0; q < 16; q++) {
      float4 c = c4[q];
      ax = dot4(c, w1r[q], ax);
      ay = dot4(c, w2r[q], ay);
    }
    X[(size_t)e * 64 + lane] = ax;
    Y[(size_t)e * 64 + lane] = ay;
  }
}

// ---------------------------------------------------------------------------
// K4: sparse-sparse product gathered at edge positions.
// tmp_matmul[e,f] = sum_j X[eid(i,j),f] * Y[eid(j,k),f], e=(i,k).
// One wave per edge: lanes scan j in chunks of 64 reading row i of eid and
// row k of eidT (both coalesced), ballot the matches (~2 per edge), then all
// 64 lanes accumulate the F=64 features for each matched pair.
// ---------------------------------------------------------------------------
__global__ __launch_bounds__(256) void k_spmm(const int* __restrict__ ei,
                                              const int* __restrict__ eid,
                                              const int* __restrict__ eidT,
                                              const float* __restrict__ X,
                                              const float* __restrict__ Y,
                                              float* __restrict__ TM) {
  int lane = threadIdx.x & 63;
  int e = (blockIdx.x * 256 + threadIdx.x) >> 6;  // one wave per edge
  int i = ei[e];
  int k = ei[NE + e];
  const int* rowI = eid + (size_t)i * NN;
  const int* rowK = eidT + (size_t)k * NN;
  float acc = 0.f;
#pragma unroll
  for (int jb = 0; jb < NN; jb += 64) {
    int e1 = rowI[jb + lane];
    int e2 = rowK[jb + lane];
    unsigned long long m = __ballot((e1 >= 0) && (e2 >= 0));
    while (m) {
      int src = (int)__builtin_ctzll(m);
      m &= m - 1;
      int s1 = __shfl(e1, src);
      int s2 = __shfl(e2, src);
      acc = fmaf(X[(size_t)s1 * 64 + lane], Y[(size_t)s2 * 64 + lane], acc);
    }
  }
  TM[(size_t)e * 64 + lane] = acc;
}

// ---------------------------------------------------------------------------
// K5: fused MLP.  out = relu([C | TM] @ W_mlp1^T) @ W_mlp2^T.
// 64 edges per block, 256 threads as 16(te) x 16(th); 4x4 register tiles.
// tmp tile (64x128) and h chunk (64x64) live in LDS (51.2 KB total, padded);
// W1/W2 stream from global (L1/L2-resident) to split LDS vs VMEM pipes.
// h is produced in 8 chunks of 64 and consumed immediately (never hits HBM).
// ---------------------------------------------------------------------------
#define GA 33  // float4 granules per tmp row (32 + 1 pad)
#define GB 17  // float4 granules per h row  (16 + 1 pad)

__global__ __launch_bounds__(256) void k_mlp(const float* __restrict__ C,
                                             const float* __restrict__ TM,
                                             const float* __restrict__ W1,
                                             const float* __restrict__ W2,
                                             float* __restrict__ out) {
  __shared__ float4 tmpS[64 * GA];
  __shared__ float4 hS[64 * GB];
  int t = threadIdx.x;
  int te = t & 15;
  int th = t >> 4;
  int base = blockIdx.x * 64;

  // stage tmp = [C | TM] for this block's 64 edges (coalesced float4)
  for (int g = t; g < 64 * 32; g += 256) {
    int e = g >> 5;
    int i4 = g & 31;
    float4 v = (i4 < 16) ? ((const float4*)C)[(size_t)(base + e) * 16 + i4]
                         : ((const float4*)TM)[(size_t)(base + e) * 16 + (i4 - 16)];
    tmpS[e * GA + i4] = v;
  }

  float oacc[4][4];
#pragma unroll
  for (int m = 0; m < 4; m++)
#pragma unroll
    for (int n = 0; n < 4; n++) oacc[m][n] = 0.f;

  const float4* W14 = (const float4*)W1;  // [512][32]
  const float4* W24 = (const float4*)W2;  // [64][128]

  for (int ch = 0; ch < 8; ch++) {
    __syncthreads();  // tmpS staged (ch=0); hS consumers done (ch>0)

    // phase A: h chunk [64 e][64 h], thread tile 4e x 4h
    float hacc[4][4];
#pragma unroll
    for (int m = 0; m < 4; m++)
#pragma unroll
      for (int n = 0; n < 4; n++) hacc[m][n] = 0.f;

    for (int i4 = 0; i4 < 32; i4++) {
      float4 tv[4], wv[4];
#pragma unroll
      for (int m = 0; m < 4; m++) tv[m] = tmpS[(te * 4 + m) * GA + i4];
#pragma unroll
      for (int n = 0; n < 4; n++)
        wv[n] = W14[(size_t)(ch * 64 + th * 4 + n) * 32 + i4];
#pragma unroll
      for (int m = 0; m < 4; m++)
#pragma unroll
        for (int n = 0; n < 4; n++) hacc[m][n] = dot4(tv[m], wv[n], hacc[m][n]);
    }

#pragma unroll
    for (int m = 0; m < 4; m++)
#pragma unroll
      for (int n = 0; n < 4; n++)
        ((float*)hS)[(te * 4 + m) * (4 * GB) + th * 4 + n] = fmaxf(hacc[m][n], 0.f);
    __syncthreads();

    // phase B: oacc += relu(h) @ W2^T over this chunk, thread tile 4e x 4o
    for (int h4 = 0; h4 < 16; h4++) {
      float4 hv[4], w2v[4];
#pragma unroll
      for (int m = 0; m < 4; m++) hv[m] = hS[(te * 4 + m) * GB + h4];
#pragma unroll
      for (int n = 0; n < 4; n++)
        w2v[n] = W24[(size_t)(th * 4 + n) * 128 + ch * 16 + h4];
#pragma unroll
      for (int m = 0; m < 4; m++)
#pragma unroll
        for (int n = 0; n < 4; n++) oacc[m][n] = dot4(hv[m], w2v[n], oacc[m][n]);
    }
  }

#pragma unroll
  for (int m = 0; m < 4; m++) {
    int e = base + te * 4 + m;
    float4 v = make_float4(oacc[m][0], oacc[m][1], oacc[m][2], oacc[m][3]);
    *((float4*)(out + (size_t)e * 64 + th * 4)) = v;
  }
}

// ---------------------------------------------------------------------------
extern "C" void kernel_launch(void* const* d_in, const int* in_sizes, int n_in,
                              void* d_out, int out_size, void* d_ws, size_t ws_size,
                              hipStream_t stream) {
  const int* ei = (const int*)d_in[0];      // [2, E]
  const float* C = (const float*)d_in[1];   // [E, 64]
  // d_in[2] = batch_node (unused)
  const float* W1 = (const float*)d_in[3];  // [64, 64]
  const float* W2 = (const float*)d_in[4];  // [64, 64]
  const float* Wm1 = (const float*)d_in[5]; // [512, 128]
  const float* Wm2 = (const float*)d_in[6]; // [64, 512]
  float* out = (float*)d_out;               // [E, 64]

  int* eid = (int*)d_ws;                    // [N*N]
  int* eidT = eid + NN * NN;                // [N*N]
  float* X = (float*)(eidT + NN * NN);      // [E, 64]
  float* Y = X + (size_t)NE * NF;           // [E, 64]
  float* TM = Y + (size_t)NE * NF;          // [E, 64]

  hipMemsetAsync(d_ws, 0xFF, (size_t)2 * NN * NN * sizeof(int), stream);
  k_scatter<<<NE / 256, 256, 0, stream>>>(ei, eid, eidT);
  k_xy<<<256, 256, 0, stream>>>(C, W1, W2, X, Y);
  k_spmm<<<(NE * 64) / 256, 256, 0, stream>>>(ei, eid, eidT, X, Y, TM);
  k_mlp<<<NE / 64, 256, 0, stream>>>(C, TM, Wm1, Wm2, out);
}

// Round 2
// 127.371 us; speedup vs baseline: 1.4546x; 1.4546x over previous
//
#include <hip/hip_runtime.h>

#define NN 512
#define NE 16384
#define NF 64

typedef __attribute__((ext_vector_type(8))) short short8_t;
typedef __attribute__((ext_vector_type(4))) float float4_t;

__device__ inline unsigned short f2bf(float f) {
  unsigned u = __builtin_bit_cast(unsigned, f);
  u += 0x7fff + ((u >> 16) & 1);  // round-to-nearest-even (finite inputs)
  return (unsigned short)(u >> 16);
}

// ---------------------------------------------------------------------------
// K1: scatter edge ids into dense [N][N] tables (forward and transposed).
// Tables pre-filled with -1 via hipMemsetAsync(0xFF).
// ---------------------------------------------------------------------------
__global__ void k_scatter(const int* __restrict__ ei,
                          int* __restrict__ eid, int* __restrict__ eidT) {
  int e = blockIdx.x * 256 + threadIdx.x;
  if (e < NE) {
    int i = ei[e];
    int k = ei[NE + e];
    eid[i * NN + k] = e;
    eidT[k * NN + i] = e;
  }
}

// ---------------------------------------------------------------------------
// K2: bf16 conversions: C -> tmpB[:,0:64], W_mlp1 -> W1B, W_mlp2 -> W2B.
// ---------------------------------------------------------------------------
__global__ __launch_bounds__(256) void k_cvt(const float* __restrict__ C,
                                             const float* __restrict__ Wm1,
                                             const float* __restrict__ Wm2,
                                             unsigned short* __restrict__ tmpB,
                                             unsigned short* __restrict__ W1B,
                                             unsigned short* __restrict__ W2B) {
  int t = blockIdx.x * 256 + threadIdx.x;
  int T = gridDim.x * 256;
  for (int i = t; i < NE * 64; i += T) {
    int e = i >> 6, f = i & 63;
    tmpB[(size_t)e * 128 + f] = f2bf(C[i]);
  }
  for (int i = t; i < 512 * 128; i += T) W1B[i] = f2bf(Wm1[i]);
  for (int i = t; i < 64 * 512; i += T) W2B[i] = f2bf(Wm2[i]);
}

// ---------------------------------------------------------------------------
// K3: X = C @ W_L1^T, Y = C @ W_L2^T (fp32, kept for spmm precision).
// ---------------------------------------------------------------------------
__device__ inline float dot4(float4 a, float4 b, float acc) {
  acc = fmaf(a.x, b.x, acc);
  acc = fmaf(a.y, b.y, acc);
  acc = fmaf(a.z, b.z, acc);
  acc = fmaf(a.w, b.w, acc);
  return acc;
}

__global__ __launch_bounds__(256) void k_xy(const float* __restrict__ C,
                                            const float* __restrict__ W1,
                                            const float* __restrict__ W2,
                                            float* __restrict__ X,
                                            float* __restrict__ Y) {
  int lane = threadIdx.x & 63;
  int wv = (blockIdx.x * 256 + threadIdx.x) >> 6;  // 0..1023
  const float4* W14 = (const float4*)W1;           // [64][16]
  const float4* W24 = (const float4*)W2;
  float4 w1r[16], w2r[16];
#pragma unroll
  for (int q = 0; q < 16; q++) {
    w1r[q] = W14[lane * 16 + q];
    w2r[q] = W24[lane * 16 + q];
  }
  for (int m = 0; m < 16; m++) {
    int e = wv * 16 + m;
    const float4* c4 = (const float4*)(C + (size_t)e * 64);
    float ax = 0.f, ay = 0.f;
#pragma unroll
    for (int q = 0; q < 16; q++) {
      float4 c = c4[q];
      ax = dot4(c, w1r[q], ax);
      ay = dot4(c, w2r[q], ay);
    }
    X[(size_t)e * 64 + lane] = ax;
    Y[(size_t)e * 64 + lane] = ay;
  }
}

// ---------------------------------------------------------------------------
// K4: sparse-sparse product gathered at edges; writes bf16 into tmpB[:,64:128].
// ---------------------------------------------------------------------------
__global__ __launch_bounds__(256) void k_spmm(const int* __restrict__ ei,
                                              const int* __restrict__ eid,
                                              const int* __restrict__ eidT,
                                              const float* __restrict__ X,
                                              const float* __restrict__ Y,
                                              unsigned short* __restrict__ tmpB) {
  int lane = threadIdx.x & 63;
  int e = (blockIdx.x * 256 + threadIdx.x) >> 6;  // one wave per edge
  int i = ei[e];
  int k = ei[NE + e];
  const int* rowI = eid + (size_t)i * NN;
  const int* rowK = eidT + (size_t)k * NN;
  float acc = 0.f;
#pragma unroll
  for (int jb = 0; jb < NN; jb += 64) {
    int e1 = rowI[jb + lane];
    int e2 = rowK[jb + lane];
    unsigned long long m = __ballot((e1 >= 0) && (e2 >= 0));
    while (m) {
      int src = (int)__builtin_ctzll(m);
      m &= m - 1;
      int s1 = __shfl(e1, src);
      int s2 = __shfl(e2, src);
      acc = fmaf(X[(size_t)s1 * 64 + lane], Y[(size_t)s2 * 64 + lane], acc);
    }
  }
  tmpB[(size_t)e * 128 + 64 + lane] = f2bf(acc);
}

// ---------------------------------------------------------------------------
// K5: fused MLP on MFMA.  out = relu(tmp @ W1^T) @ W2^T, tmp=[C|TM] bf16.
// Block = 4 waves x 16 edges = 64 edges. Hidden processed in 8 chunks of 64.
// GEMM1 computed transposed (hT = W1 . tmp^T): D row=hid, col=edge, so regs
// r=0..3 are consecutive hid -> one ds_write_b64 per tile into hS[edge][hid].
// GEMM2 reads hS rows as A-fragments via ds_read_b128. W1/W2 chunks staged in
// LDS with +16B row padding (272B/144B strides -> only free 2-way aliasing).
// ---------------------------------------------------------------------------
__global__ __launch_bounds__(256) void k_mlp_mfma(
    const unsigned short* __restrict__ tmpB,  // [NE][128]
    const unsigned short* __restrict__ W1B,   // [512][128]
    const unsigned short* __restrict__ W2B,   // [64][512]
    float* __restrict__ out) {                // [NE][64]
  __shared__ __attribute__((aligned(16))) unsigned short W1s[64 * 136];
  __shared__ __attribute__((aligned(16))) unsigned short W2s[64 * 72];
  __shared__ __attribute__((aligned(16))) unsigned short hS[4][16 * 72];

  int t = threadIdx.x;
  int w = t >> 6;
  int lane = t & 63;
  int col = lane & 15;
  int q = lane >> 4;
  int base_e = blockIdx.x * 64 + w * 16;

  // preload tmp B-fragments: B[k][edge], lane holds edge=col, k=ks*32+q*8+j
  short8_t btmp[4];
#pragma unroll
  for (int ks = 0; ks < 4; ks++)
    btmp[ks] = *(const short8_t*)(tmpB + (size_t)(base_e + col) * 128 + ks * 32 + q * 8);

  float4_t oacc[4];
#pragma unroll
  for (int ft = 0; ft < 4; ft++) oacc[ft] = (float4_t){0.f, 0.f, 0.f, 0.f};

  for (int ch = 0; ch < 8; ch++) {
    __syncthreads();  // previous chunk's consumers done
    {  // stage W1 chunk [64 hid][128 k] and W2 chunk [64 fo][64 hid]
      float4* d1 = (float4*)W1s;
      const float4* s1 = (const float4*)W1B;
#pragma unroll
      for (int it = 0; it < 4; it++) {
        int g = it * 256 + t;  // 1024 granules of 16B
        int r = g >> 4, c4 = g & 15;
        d1[r * 17 + c4] = s1[(size_t)(ch * 64 + r) * 16 + c4];
      }
      float4* d2 = (float4*)W2s;
      const float4* s2 = (const float4*)W2B;
#pragma unroll
      for (int it = 0; it < 2; it++) {
        int g = it * 256 + t;  // 512 granules
        int r = g >> 3, c4 = g & 7;
        d2[r * 9 + c4] = s2[(size_t)r * 64 + ch * 8 + c4];
      }
    }
    __syncthreads();

    // GEMM1: hT[hid][edge] for 64 hid; A = W1 rows, B = tmp rows
#pragma unroll
    for (int ht = 0; ht < 4; ht++) {
      float4_t hacc = (float4_t){0.f, 0.f, 0.f, 0.f};
#pragma unroll
      for (int ks = 0; ks < 4; ks++) {
        short8_t af = *(const short8_t*)(W1s + (ht * 16 + col) * 136 + ks * 32 + q * 8);
        hacc = __builtin_amdgcn_mfma_f32_16x16x32_bf16(af, btmp[ks], hacc, 0, 0, 0);
      }
      short4 hp;  // regs r=0..3 -> hid ht*16+q*4+r (consecutive), edge=col
      hp.x = (short)f2bf(fmaxf(hacc[0], 0.f));
      hp.y = (short)f2bf(fmaxf(hacc[1], 0.f));
      hp.z = (short)f2bf(fmaxf(hacc[2], 0.f));
      hp.w = (short)f2bf(fmaxf(hacc[3], 0.f));
      *(short4*)(&hS[w][col * 72 + ht * 16 + q * 4]) = hp;
    }
    __syncthreads();

    // GEMM2: out[edge][fo] += h[edge][:64] @ W2^T chunk
#pragma unroll
    for (int ks2 = 0; ks2 < 2; ks2++) {
      short8_t a2 = *(const short8_t*)(&hS[w][col * 72 + ks2 * 32 + q * 8]);
#pragma unroll
      for (int ft = 0; ft < 4; ft++) {
        short8_t b2 = *(const short8_t*)(W2s + (ft * 16 + col) * 72 + ks2 * 32 + q * 8);
        oacc[ft] = __builtin_amdgcn_mfma_f32_16x16x32_bf16(a2, b2, oacc[ft], 0, 0, 0);
      }
    }
  }

  // D: row=q*4+r -> edge, col -> fo
#pragma unroll
  for (int ft = 0; ft < 4; ft++)
#pragma unroll
    for (int r = 0; r < 4; r++)
      out[(size_t)(base_e + q * 4 + r) * 64 + ft * 16 + col] = oacc[ft][r];
}

// ---------------------------------------------------------------------------
extern "C" void kernel_launch(void* const* d_in, const int* in_sizes, int n_in,
                              void* d_out, int out_size, void* d_ws, size_t ws_size,
                              hipStream_t stream) {
  const int* ei = (const int*)d_in[0];       // [2, E]
  const float* C = (const float*)d_in[1];    // [E, 64]
  const float* W1 = (const float*)d_in[3];   // [64, 64]
  const float* W2 = (const float*)d_in[4];   // [64, 64]
  const float* Wm1 = (const float*)d_in[5];  // [512, 128]
  const float* Wm2 = (const float*)d_in[6];  // [64, 512]
  float* out = (float*)d_out;                // [E, 64]

  char* p = (char*)d_ws;
  int* eid = (int*)p;                 p += (size_t)NN * NN * 4;
  int* eidT = (int*)p;                p += (size_t)NN * NN * 4;
  float* X = (float*)p;               p += (size_t)NE * NF * 4;
  float* Y = (float*)p;               p += (size_t)NE * NF * 4;
  unsigned short* tmpB = (unsigned short*)p;  p += (size_t)NE * 128 * 2;
  unsigned short* W1B = (unsigned short*)p;   p += (size_t)512 * 128 * 2;
  unsigned short* W2B = (unsigned short*)p;   p += (size_t)64 * 512 * 2;

  hipMemsetAsync(eid, 0xFF, (size_t)2 * NN * NN * sizeof(int), stream);
  k_scatter<<<NE / 256, 256, 0, stream>>>(ei, eid, eidT);
  k_cvt<<<512, 256, 0, stream>>>(C, Wm1, Wm2, tmpB, W1B, W2B);
  k_xy<<<256, 256, 0, stream>>>(C, W1, W2, X, Y);
  k_spmm<<<(NE * 64) / 256, 256, 0, stream>>>(ei, eid, eidT, X, Y, tmpB);
  k_mlp_mfma<<<NE / 64, 256, 0, stream>>>(tmpB, W1B, W2B, out);
}

// Round 3
// 101.932 us; speedup vs baseline: 1.8176x; 1.2496x over previous
//
#include <hip/hip_runtime.h>

#define NN 512
#define NE 16384
#define NF 64

typedef __attribute__((ext_vector_type(8))) short short8_t;
typedef __attribute__((ext_vector_type(4))) float float4_t;

__device__ inline unsigned short f2bf(float f) {
  unsigned u = __builtin_bit_cast(unsigned, f);
  u += 0x7fff + ((u >> 16) & 1);  // round-to-nearest-even (finite inputs)
  return (unsigned short)(u >> 16);
}

// ---------------------------------------------------------------------------
// K1: blocks [0,64): scatter edge ids into [N][N] tables (pre-memset to -1).
//     blocks [64,192): convert W_mlp1/W_mlp2 to bf16.
// ---------------------------------------------------------------------------
__global__ __launch_bounds__(256) void k_prep(const int* __restrict__ ei,
                                              const float* __restrict__ Wm1,
                                              const float* __restrict__ Wm2,
                                              int* __restrict__ eid,
                                              int* __restrict__ eidT,
                                              unsigned short* __restrict__ W1B,
                                              unsigned short* __restrict__ W2B) {
  int b = blockIdx.x;
  if (b < 64) {
    int e = b * 256 + threadIdx.x;
    int i = ei[e];
    int k = ei[NE + e];
    eid[i * NN + k] = e;
    eidT[k * NN + i] = e;
  } else {
    int t = (b - 64) * 256 + threadIdx.x;  // 0..32767
    for (int i = t; i < 512 * 128; i += 128 * 256) W1B[i] = f2bf(Wm1[i]);
    for (int i = t; i < 64 * 512; i += 128 * 256) W2B[i] = f2bf(Wm2[i]);
  }
}

// ---------------------------------------------------------------------------
// K2: X = C@W_L1^T, Y = C@W_L2^T via bf16 MFMA (fp32 out), fused with the
// C -> bf16 tmpB[:,0:64] conversion (C rows are loaded in B-frag order
// anyway). W1/W2 staged once per block into LDS as bf16 (+8 short pad ->
// worst 2-way bank aliasing = free). Block = 4 waves x 16 edges.
// ---------------------------------------------------------------------------
__global__ __launch_bounds__(256) void k_xy_mfma(const float* __restrict__ C,
                                                 const float* __restrict__ W1,
                                                 const float* __restrict__ W2,
                                                 float* __restrict__ X,
                                                 float* __restrict__ Y,
                                                 unsigned short* __restrict__ tmpB) {
  __shared__ __attribute__((aligned(16))) short W1s[64 * 72];
  __shared__ __attribute__((aligned(16))) short W2s[64 * 72];
  int t = threadIdx.x;
  int w = t >> 6;
  int lane = t & 63;
  int col = lane & 15;
  int q = lane >> 4;
  int base_e = blockIdx.x * 64 + w * 16;

  // stage W1,W2 (fp32 global -> bf16 LDS), 64 rows x 16 float4 granules
#pragma unroll
  for (int z = 0; z < 4; z++) {
    int gi = z * 256 + t;
    int r = gi >> 4, c = gi & 15;
    float4 v1 = ((const float4*)W1)[r * 16 + c];
    float4 v2 = ((const float4*)W2)[r * 16 + c];
    short4 s1, s2;
    s1.x = f2bf(v1.x); s1.y = f2bf(v1.y); s1.z = f2bf(v1.z); s1.w = f2bf(v1.w);
    s2.x = f2bf(v2.x); s2.y = f2bf(v2.y); s2.z = f2bf(v2.z); s2.w = f2bf(v2.w);
    *(short4*)(W1s + r * 72 + c * 4) = s1;
    *(short4*)(W2s + r * 72 + c * 4) = s2;
  }
  __syncthreads();

  // load C rows (fp32), convert, write tmpB, keep as B-fragments
  short8_t bfrag[2];
#pragma unroll
  for (int ks = 0; ks < 2; ks++) {
    float4 c0 = ((const float4*)C)[(size_t)(base_e + col) * 16 + ks * 8 + q * 2];
    float4 c1 = ((const float4*)C)[(size_t)(base_e + col) * 16 + ks * 8 + q * 2 + 1];
    short8_t s;
    s[0] = (short)f2bf(c0.x); s[1] = (short)f2bf(c0.y);
    s[2] = (short)f2bf(c0.z); s[3] = (short)f2bf(c0.w);
    s[4] = (short)f2bf(c1.x); s[5] = (short)f2bf(c1.y);
    s[6] = (short)f2bf(c1.z); s[7] = (short)f2bf(c1.w);
    bfrag[ks] = s;
    *(short8_t*)(tmpB + (size_t)(base_e + col) * 128 + ks * 32 + q * 8) = s;
  }

  float4_t xa[4], ya[4];
#pragma unroll
  for (int ft = 0; ft < 4; ft++) {
    xa[ft] = (float4_t){0.f, 0.f, 0.f, 0.f};
    ya[ft] = (float4_t){0.f, 0.f, 0.f, 0.f};
  }
#pragma unroll
  for (int ks = 0; ks < 2; ks++) {
#pragma unroll
    for (int ft = 0; ft < 4; ft++) {
      short8_t a1 = *(const short8_t*)(W1s + (ft * 16 + col) * 72 + ks * 32 + q * 8);
      short8_t a2 = *(const short8_t*)(W2s + (ft * 16 + col) * 72 + ks * 32 + q * 8);
      xa[ft] = __builtin_amdgcn_mfma_f32_16x16x32_bf16(a1, bfrag[ks], xa[ft], 0, 0, 0);
      ya[ft] = __builtin_amdgcn_mfma_f32_16x16x32_bf16(a2, bfrag[ks], ya[ft], 0, 0, 0);
    }
  }
  // D[row=q*4+r -> f in tile][col -> edge]; f contiguous across regs -> float4
#pragma unroll
  for (int ft = 0; ft < 4; ft++) {
    float4 vx = make_float4(xa[ft][0], xa[ft][1], xa[ft][2], xa[ft][3]);
    float4 vy = make_float4(ya[ft][0], ya[ft][1], ya[ft][2], ya[ft][3]);
    *(float4*)(X + (size_t)(base_e + col) * 64 + ft * 16 + q * 4) = vx;
    *(float4*)(Y + (size_t)(base_e + col) * 64 + ft * 16 + q * 4) = vy;
  }
}

// ---------------------------------------------------------------------------
// K3: sparse-sparse product gathered at edges; writes bf16 into tmpB[:,64:128].
// One wave per edge; coalesced row scans of L2-resident id tables; ~2 matches
// per edge handled via ballot + shfl broadcast.
// ---------------------------------------------------------------------------
__global__ __launch_bounds__(256) void k_spmm(const int* __restrict__ ei,
                                              const int* __restrict__ eid,
                                              const int* __restrict__ eidT,
                                              const float* __restrict__ X,
                                              const float* __restrict__ Y,
                                              unsigned short* __restrict__ tmpB) {
  int lane = threadIdx.x & 63;
  int e = (blockIdx.x * 256 + threadIdx.x) >> 6;
  int i = ei[e];
  int k = ei[NE + e];
  const int* rowI = eid + (size_t)i * NN;
  const int* rowK = eidT + (size_t)k * NN;
  float acc = 0.f;
#pragma unroll
  for (int jb = 0; jb < NN; jb += 64) {
    int e1 = rowI[jb + lane];
    int e2 = rowK[jb + lane];
    unsigned long long m = __ballot((e1 >= 0) && (e2 >= 0));
    while (m) {
      int src = (int)__builtin_ctzll(m);
      m &= m - 1;
      int s1 = __shfl(e1, src);
      int s2 = __shfl(e2, src);
      acc = fmaf(X[(size_t)s1 * 64 + lane], Y[(size_t)s2 * 64 + lane], acc);
    }
  }
  tmpB[(size_t)e * 128 + 64 + lane] = f2bf(acc);
}

// ---------------------------------------------------------------------------
// K4: fused MLP on MFMA, hidden-split for occupancy.
// Block = 256 thr = 4 waves = 2 edge-groups (g) x 2 hidden-halves (h);
// block covers 32 edges, grid = 512 -> 2 blocks/CU, 8 waves/CU (was 4).
// Each iteration stages TWO 64-hid chunks of W1 (halves' chunks it and 4+it)
// and the matching W2 columns; wave (g,h) computes hT = W1.tmp^T for its
// chunk (D row=hid col=edge -> ds_write_b64 into hS[edge][hid]), then
// oacc += relu(h)@W2^T. After 4 iterations h=1 waves pass partial oacc to
// h=0 waves through LDS (stride 66 floats -> 2-way max).
// ---------------------------------------------------------------------------
__global__ __launch_bounds__(256) void k_mlp2(
    const unsigned short* __restrict__ tmpB,  // [NE][128]
    const unsigned short* __restrict__ W1B,   // [512][128]
    const unsigned short* __restrict__ W2B,   // [64][512]
    float* __restrict__ out) {                // [NE][64]
  __shared__ __attribute__((aligned(16))) short W1s[128 * 136];  // 34816 B
  __shared__ __attribute__((aligned(16))) short W2s[64 * 136];   // 17408 B
  __shared__ __attribute__((aligned(16))) short hS[4][16 * 72];  //  9216 B

  int t = threadIdx.x;
  int w = t >> 6;
  int lane = t & 63;
  int col = lane & 15;
  int q = lane >> 4;
  int g = w & 1;
  int h = w >> 1;
  int base_e = blockIdx.x * 32 + g * 16;

  // B-fragments: tmp rows, B[k][edge=col], k = ks*32 + q*8 + j
  short8_t btmp[4];
#pragma unroll
  for (int ks = 0; ks < 4; ks++)
    btmp[ks] = *(const short8_t*)(tmpB + (size_t)(base_e + col) * 128 + ks * 32 + q * 8);

  float4_t oacc[4];
#pragma unroll
  for (int ft = 0; ft < 4; ft++) oacc[ft] = (float4_t){0.f, 0.f, 0.f, 0.f};

  for (int it = 0; it < 4; it++) {
    __syncthreads();  // previous iteration's W1s/W2s consumers done
    {  // stage W1 rows of chunks (it) and (4+it): 128 rows x 16 uint4
      uint4* d1 = (uint4*)W1s;
      const uint4* s1 = (const uint4*)W1B;
#pragma unroll
      for (int z = 0; z < 8; z++) {
        int gi = z * 256 + t;
        int r = gi >> 4, c = gi & 15;
        int grow = ((r >> 6) * 4 + it) * 64 + (r & 63);
        d1[r * 17 + c] = s1[(size_t)grow * 16 + c];
      }
      // stage W2 cols of both chunks: 64 rows x 16 uint4 (8 per chunk)
      uint4* d2 = (uint4*)W2s;
      const uint4* s2 = (const uint4*)W2B;
#pragma unroll
      for (int z = 0; z < 4; z++) {
        int gi = z * 256 + t;
        int r = gi >> 4, c = gi & 15;
        int gc = ((c >> 3) * 4 + it) * 8 + (c & 7);
        d2[r * 17 + c] = s2[(size_t)r * 64 + gc];
      }
    }
    __syncthreads();

    // GEMM1: hT[hid][edge] for this half's 64-hid chunk
#pragma unroll
    for (int ht = 0; ht < 4; ht++) {
      float4_t hacc = (float4_t){0.f, 0.f, 0.f, 0.f};
#pragma unroll
      for (int ks = 0; ks < 4; ks++) {
        short8_t af = *(const short8_t*)(W1s + (h * 64 + ht * 16 + col) * 136 + ks * 32 + q * 8);
        hacc = __builtin_amdgcn_mfma_f32_16x16x32_bf16(af, btmp[ks], hacc, 0, 0, 0);
      }
      short4 hp;  // regs r=0..3 -> hid ht*16+q*4+r (consecutive), edge=col
      hp.x = (short)f2bf(fmaxf(hacc[0], 0.f));
      hp.y = (short)f2bf(fmaxf(hacc[1], 0.f));
      hp.z = (short)f2bf(fmaxf(hacc[2], 0.f));
      hp.w = (short)f2bf(fmaxf(hacc[3], 0.f));
      *(short4*)(&hS[w][col * 72 + ht * 16 + q * 4]) = hp;
    }
    // hS is per-wave: no block barrier needed before GEMM2 (lgkmcnt only)

    // GEMM2: oacc += relu(h) @ W2^T over this half's chunk
#pragma unroll
    for (int ks2 = 0; ks2 < 2; ks2++) {
      short8_t a2 = *(const short8_t*)(&hS[w][col * 72 + ks2 * 32 + q * 8]);
#pragma unroll
      for (int ft = 0; ft < 4; ft++) {
        short8_t b2 = *(const short8_t*)(W2s + (ft * 16 + col) * 136 + h * 64 + ks2 * 32 + q * 8);
        oacc[ft] = __builtin_amdgcn_mfma_f32_16x16x32_bf16(a2, b2, oacc[ft], 0, 0, 0);
      }
    }
  }

  // cross-half reduction via LDS (reuse W1s), then store
  __syncthreads();
  float* red = (float*)W1s;  // [32 edges][stride 66] fp32
  if (h == 1) {
#pragma unroll
    for (int ft = 0; ft < 4; ft++)
#pragma unroll
      for (int r = 0; r < 4; r++)
        red[(g * 16 + q * 4 + r) * 66 + ft * 16 + col] = oacc[ft][r];
  }
  __syncthreads();
  if (h == 0) {
#pragma unroll
    for (int ft = 0; ft < 4; ft++)
#pragma unroll
      for (int r = 0; r < 4; r++) {
        float v = oacc[ft][r] + red[(g * 16 + q * 4 + r) * 66 + ft * 16 + col];
        out[(size_t)(base_e + q * 4 + r) * 64 + ft * 16 + col] = v;
      }
  }
}

// ---------------------------------------------------------------------------
extern "C" void kernel_launch(void* const* d_in, const int* in_sizes, int n_in,
                              void* d_out, int out_size, void* d_ws, size_t ws_size,
                              hipStream_t stream) {
  const int* ei = (const int*)d_in[0];       // [2, E]
  const float* C = (const float*)d_in[1];    // [E, 64]
  const float* W1 = (const float*)d_in[3];   // [64, 64]
  const float* W2 = (const float*)d_in[4];   // [64, 64]
  const float* Wm1 = (const float*)d_in[5];  // [512, 128]
  const float* Wm2 = (const float*)d_in[6];  // [64, 512]
  float* out = (float*)d_out;                // [E, 64]

  char* p = (char*)d_ws;
  int* eid = (int*)p;                 p += (size_t)NN * NN * 4;
  int* eidT = (int*)p;                p += (size_t)NN * NN * 4;
  float* X = (float*)p;               p += (size_t)NE * NF * 4;
  float* Y = (float*)p;               p += (size_t)NE * NF * 4;
  unsigned short* tmpB = (unsigned short*)p;  p += (size_t)NE * 128 * 2;
  unsigned short* W1B = (unsigned short*)p;   p += (size_t)512 * 128 * 2;
  unsigned short* W2B = (unsigned short*)p;   p += (size_t)64 * 512 * 2;

  hipMemsetAsync(eid, 0xFF, (size_t)2 * NN * NN * sizeof(int), stream);
  k_prep<<<192, 256, 0, stream>>>(ei, Wm1, Wm2, eid, eidT, W1B, W2B);
  k_xy_mfma<<<NE / 64, 256, 0, stream>>>(C, W1, W2, X, Y, tmpB);
  k_spmm<<<(NE * 64) / 256, 256, 0, stream>>>(ei, eid, eidT, X, Y, tmpB);
  k_mlp2<<<NE / 32, 256, 0, stream>>>(tmpB, W1B, W2B, out);
}

// Round 4
// 99.280 us; speedup vs baseline: 1.8662x; 1.0267x over previous
//
#include <hip/hip_runtime.h>

#define NN 512
#define NE 16384
#define NF 64

typedef __attribute__((ext_vector_type(8))) short short8_t;
typedef __attribute__((ext_vector_type(4))) float float4_t;

__device__ inline unsigned short f2bf(float f) {
  unsigned u = __builtin_bit_cast(unsigned, f);
  u += 0x7fff + ((u >> 16) & 1);  // round-to-nearest-even (finite inputs)
  return (unsigned short)(u >> 16);
}

// ---------------------------------------------------------------------------
// K1: clear eid/eidT tables to -1 (2 MB, one uint4 store pair per thread)
//     + convert W_mlp1/W_mlp2 to bf16. Replaces hipMemsetAsync + k_prep.
// Grid: 256 blocks x 256 thr = 65536 threads.
// ---------------------------------------------------------------------------
__global__ __launch_bounds__(256) void k_init(const float* __restrict__ Wm1,
                                              const float* __restrict__ Wm2,
                                              uint4* __restrict__ tabs,  // eid|eidT
                                              unsigned short* __restrict__ W1B,
                                              unsigned short* __restrict__ W2B) {
  int t = blockIdx.x * 256 + threadIdx.x;  // 0..65535
  uint4 m1 = make_uint4(~0u, ~0u, ~0u, ~0u);
  tabs[t] = m1;
  tabs[t + 65536] = m1;
  if (t < 16384) {  // W1B: 512*128 floats = 16384 float4
    float4 v = ((const float4*)Wm1)[t];
    short4 s;
    s.x = f2bf(v.x); s.y = f2bf(v.y); s.z = f2bf(v.z); s.w = f2bf(v.w);
    ((short4*)W1B)[t] = s;
  } else if (t < 24576) {  // W2B: 64*512 floats = 8192 float4
    int i = t - 16384;
    float4 v = ((const float4*)Wm2)[i];
    short4 s;
    s.x = f2bf(v.x); s.y = f2bf(v.y); s.z = f2bf(v.z); s.w = f2bf(v.w);
    ((short4*)W2B)[i] = s;
  }
}

// ---------------------------------------------------------------------------
// K2: X = C@W_L1^T, Y = C@W_L2^T via bf16 MFMA (fp32 out), fused with
// C -> bf16 tmpB[:,0:64] conversion AND the edge-id scatter (first 64
// threads handle this block's 64 edges; independent of the MFMA path).
// W1/W2 staged once per block into LDS as bf16 (+8 short pad -> free 2-way
// aliasing). Block = 4 waves x 16 edges.
// ---------------------------------------------------------------------------
__global__ __launch_bounds__(256) void k_xy_mfma(const float* __restrict__ C,
                                                 const float* __restrict__ W1,
                                                 const float* __restrict__ W2,
                                                 const int* __restrict__ ei,
                                                 int* __restrict__ eid,
                                                 int* __restrict__ eidT,
                                                 float* __restrict__ X,
                                                 float* __restrict__ Y,
                                                 unsigned short* __restrict__ tmpB) {
  __shared__ __attribute__((aligned(16))) short W1s[64 * 72];
  __shared__ __attribute__((aligned(16))) short W2s[64 * 72];
  int t = threadIdx.x;
  int w = t >> 6;
  int lane = t & 63;
  int col = lane & 15;
  int q = lane >> 4;
  int base_e = blockIdx.x * 64 + w * 16;

  // scatter this block's 64 edges into the (cleared) id tables
  if (t < 64) {
    int e = blockIdx.x * 64 + t;
    int i = ei[e];
    int k = ei[NE + e];
    eid[i * NN + k] = e;
    eidT[k * NN + i] = e;
  }

  // stage W1,W2 (fp32 global -> bf16 LDS), 64 rows x 16 float4 granules
#pragma unroll
  for (int z = 0; z < 4; z++) {
    int gi = z * 256 + t;
    int r = gi >> 4, c = gi & 15;
    float4 v1 = ((const float4*)W1)[r * 16 + c];
    float4 v2 = ((const float4*)W2)[r * 16 + c];
    short4 s1, s2;
    s1.x = f2bf(v1.x); s1.y = f2bf(v1.y); s1.z = f2bf(v1.z); s1.w = f2bf(v1.w);
    s2.x = f2bf(v2.x); s2.y = f2bf(v2.y); s2.z = f2bf(v2.z); s2.w = f2bf(v2.w);
    *(short4*)(W1s + r * 72 + c * 4) = s1;
    *(short4*)(W2s + r * 72 + c * 4) = s2;
  }
  __syncthreads();

  // load C rows (fp32), convert, write tmpB, keep as B-fragments
  short8_t bfrag[2];
#pragma unroll
  for (int ks = 0; ks < 2; ks++) {
    float4 c0 = ((const float4*)C)[(size_t)(base_e + col) * 16 + ks * 8 + q * 2];
    float4 c1 = ((const float4*)C)[(size_t)(base_e + col) * 16 + ks * 8 + q * 2 + 1];
    short8_t s;
    s[0] = (short)f2bf(c0.x); s[1] = (short)f2bf(c0.y);
    s[2] = (short)f2bf(c0.z); s[3] = (short)f2bf(c0.w);
    s[4] = (short)f2bf(c1.x); s[5] = (short)f2bf(c1.y);
    s[6] = (short)f2bf(c1.z); s[7] = (short)f2bf(c1.w);
    bfrag[ks] = s;
    *(short8_t*)(tmpB + (size_t)(base_e + col) * 128 + ks * 32 + q * 8) = s;
  }

  float4_t xa[4], ya[4];
#pragma unroll
  for (int ft = 0; ft < 4; ft++) {
    xa[ft] = (float4_t){0.f, 0.f, 0.f, 0.f};
    ya[ft] = (float4_t){0.f, 0.f, 0.f, 0.f};
  }
#pragma unroll
  for (int ks = 0; ks < 2; ks++) {
#pragma unroll
    for (int ft = 0; ft < 4; ft++) {
      short8_t a1 = *(const short8_t*)(W1s + (ft * 16 + col) * 72 + ks * 32 + q * 8);
      short8_t a2 = *(const short8_t*)(W2s + (ft * 16 + col) * 72 + ks * 32 + q * 8);
      xa[ft] = __builtin_amdgcn_mfma_f32_16x16x32_bf16(a1, bfrag[ks], xa[ft], 0, 0, 0);
      ya[ft] = __builtin_amdgcn_mfma_f32_16x16x32_bf16(a2, bfrag[ks], ya[ft], 0, 0, 0);
    }
  }
  // D[row=q*4+r -> f in tile][col -> edge]; f contiguous across regs -> float4
#pragma unroll
  for (int ft = 0; ft < 4; ft++) {
    float4 vx = make_float4(xa[ft][0], xa[ft][1], xa[ft][2], xa[ft][3]);
    float4 vy = make_float4(ya[ft][0], ya[ft][1], ya[ft][2], ya[ft][3]);
    *(float4*)(X + (size_t)(base_e + col) * 64 + ft * 16 + q * 4) = vx;
    *(float4*)(Y + (size_t)(base_e + col) * 64 + ft * 16 + q * 4) = vy;
  }
}

// ---------------------------------------------------------------------------
// K3: sparse-sparse product gathered at edges; writes bf16 into tmpB[:,64:128].
// One wave per edge; coalesced row scans of L2-resident id tables; ~2 matches
// per edge handled via ballot + shfl broadcast.
// ---------------------------------------------------------------------------
__global__ __launch_bounds__(256) void k_spmm(const int* __restrict__ ei,
                                              const int* __restrict__ eid,
                                              const int* __restrict__ eidT,
                                              const float* __restrict__ X,
                                              const float* __restrict__ Y,
                                              unsigned short* __restrict__ tmpB) {
  int lane = threadIdx.x & 63;
  int e = (blockIdx.x * 256 + threadIdx.x) >> 6;
  int i = ei[e];
  int k = ei[NE + e];
  const int* rowI = eid + (size_t)i * NN;
  const int* rowK = eidT + (size_t)k * NN;
  float acc = 0.f;
#pragma unroll
  for (int jb = 0; jb < NN; jb += 64) {
    int e1 = rowI[jb + lane];
    int e2 = rowK[jb + lane];
    unsigned long long m = __ballot((e1 >= 0) && (e2 >= 0));
    while (m) {
      int src = (int)__builtin_ctzll(m);
      m &= m - 1;
      int s1 = __shfl(e1, src);
      int s2 = __shfl(e2, src);
      acc = fmaf(X[(size_t)s1 * 64 + lane], Y[(size_t)s2 * 64 + lane], acc);
    }
  }
  tmpB[(size_t)e * 128 + 64 + lane] = f2bf(acc);
}

// ---------------------------------------------------------------------------
// K4: fused MLP on MFMA, hidden-split for occupancy.
// Block = 256 thr = 4 waves = 2 edge-groups (g) x 2 hidden-halves (h);
// block covers 32 edges, grid = 512 -> 2 blocks/CU, 8 waves/CU.
// Each iteration stages TWO 64-hid chunks of W1 (halves' chunks it and 4+it)
// and the matching W2 columns; wave (g,h) computes hT = W1.tmp^T for its
// chunk (D row=hid col=edge -> ds_write_b64 into hS[edge][hid]), then
// oacc += relu(h)@W2^T. After 4 iterations h=1 waves pass partial oacc to
// h=0 waves through LDS (stride 66 floats -> 2-way max).
// ---------------------------------------------------------------------------
__global__ __launch_bounds__(256) void k_mlp2(
    const unsigned short* __restrict__ tmpB,  // [NE][128]
    const unsigned short* __restrict__ W1B,   // [512][128]
    const unsigned short* __restrict__ W2B,   // [64][512]
    float* __restrict__ out) {                // [NE][64]
  __shared__ __attribute__((aligned(16))) short W1s[128 * 136];  // 34816 B
  __shared__ __attribute__((aligned(16))) short W2s[64 * 136];   // 17408 B
  __shared__ __attribute__((aligned(16))) short hS[4][16 * 72];  //  9216 B

  int t = threadIdx.x;
  int w = t >> 6;
  int lane = t & 63;
  int col = lane & 15;
  int q = lane >> 4;
  int g = w & 1;
  int h = w >> 1;
  int base_e = blockIdx.x * 32 + g * 16;

  // B-fragments: tmp rows, B[k][edge=col], k = ks*32 + q*8 + j
  short8_t btmp[4];
#pragma unroll
  for (int ks = 0; ks < 4; ks++)
    btmp[ks] = *(const short8_t*)(tmpB + (size_t)(base_e + col) * 128 + ks * 32 + q * 8);

  float4_t oacc[4];
#pragma unroll
  for (int ft = 0; ft < 4; ft++) oacc[ft] = (float4_t){0.f, 0.f, 0.f, 0.f};

  for (int it = 0; it < 4; it++) {
    __syncthreads();  // previous iteration's W1s/W2s consumers done
    {  // stage W1 rows of chunks (it) and (4+it): 128 rows x 16 uint4
      uint4* d1 = (uint4*)W1s;
      const uint4* s1 = (const uint4*)W1B;
#pragma unroll
      for (int z = 0; z < 8; z++) {
        int gi = z * 256 + t;
        int r = gi >> 4, c = gi & 15;
        int grow = ((r >> 6) * 4 + it) * 64 + (r & 63);
        d1[r * 17 + c] = s1[(size_t)grow * 16 + c];
      }
      // stage W2 cols of both chunks: 64 rows x 16 uint4 (8 per chunk)
      uint4* d2 = (uint4*)W2s;
      const uint4* s2 = (const uint4*)W2B;
#pragma unroll
      for (int z = 0; z < 4; z++) {
        int gi = z * 256 + t;
        int r = gi >> 4, c = gi & 15;
        int gc = ((c >> 3) * 4 + it) * 8 + (c & 7);
        d2[r * 17 + c] = s2[(size_t)r * 64 + gc];
      }
    }
    __syncthreads();

    // GEMM1: hT[hid][edge] for this half's 64-hid chunk
#pragma unroll
    for (int ht = 0; ht < 4; ht++) {
      float4_t hacc = (float4_t){0.f, 0.f, 0.f, 0.f};
#pragma unroll
      for (int ks = 0; ks < 4; ks++) {
        short8_t af = *(const short8_t*)(W1s + (h * 64 + ht * 16 + col) * 136 + ks * 32 + q * 8);
        hacc = __builtin_amdgcn_mfma_f32_16x16x32_bf16(af, btmp[ks], hacc, 0, 0, 0);
      }
      short4 hp;  // regs r=0..3 -> hid ht*16+q*4+r (consecutive), edge=col
      hp.x = (short)f2bf(fmaxf(hacc[0], 0.f));
      hp.y = (short)f2bf(fmaxf(hacc[1], 0.f));
      hp.z = (short)f2bf(fmaxf(hacc[2], 0.f));
      hp.w = (short)f2bf(fmaxf(hacc[3], 0.f));
      *(short4*)(&hS[w][col * 72 + ht * 16 + q * 4]) = hp;
    }
    // hS is per-wave: no block barrier needed before GEMM2 (lgkmcnt only)

    // GEMM2: oacc += relu(h) @ W2^T over this half's chunk
#pragma unroll
    for (int ks2 = 0; ks2 < 2; ks2++) {
      short8_t a2 = *(const short8_t*)(&hS[w][col * 72 + ks2 * 32 + q * 8]);
#pragma unroll
      for (int ft = 0; ft < 4; ft++) {
        short8_t b2 = *(const short8_t*)(W2s + (ft * 16 + col) * 136 + h * 64 + ks2 * 32 + q * 8);
        oacc[ft] = __builtin_amdgcn_mfma_f32_16x16x32_bf16(a2, b2, oacc[ft], 0, 0, 0);
      }
    }
  }

  // cross-half reduction via LDS (reuse W1s), then store
  __syncthreads();
  float* red = (float*)W1s;  // [32 edges][stride 66] fp32
  if (h == 1) {
#pragma unroll
    for (int ft = 0; ft < 4; ft++)
#pragma unroll
      for (int r = 0; r < 4; r++)
        red[(g * 16 + q * 4 + r) * 66 + ft * 16 + col] = oacc[ft][r];
  }
  __syncthreads();
  if (h == 0) {
#pragma unroll
    for (int ft = 0; ft < 4; ft++)
#pragma unroll
      for (int r = 0; r < 4; r++) {
        float v = oacc[ft][r] + red[(g * 16 + q * 4 + r) * 66 + ft * 16 + col];
        out[(size_t)(base_e + q * 4 + r) * 64 + ft * 16 + col] = v;
      }
  }
}

// ---------------------------------------------------------------------------
extern "C" void kernel_launch(void* const* d_in, const int* in_sizes, int n_in,
                              void* d_out, int out_size, void* d_ws, size_t ws_size,
                              hipStream_t stream) {
  const int* ei = (const int*)d_in[0];       // [2, E]
  const float* C = (const float*)d_in[1];    // [E, 64]
  const float* W1 = (const float*)d_in[3];   // [64, 64]
  const float* W2 = (const float*)d_in[4];   // [64, 64]
  const float* Wm1 = (const float*)d_in[5];  // [512, 128]
  const float* Wm2 = (const float*)d_in[6];  // [64, 512]
  float* out = (float*)d_out;                // [E, 64]

  char* p = (char*)d_ws;
  int* eid = (int*)p;                 p += (size_t)NN * NN * 4;
  int* eidT = (int*)p;                p += (size_t)NN * NN * 4;
  float* X = (float*)p;               p += (size_t)NE * NF * 4;
  float* Y = (float*)p;               p += (size_t)NE * NF * 4;
  unsigned short* tmpB = (unsigned short*)p;  p += (size_t)NE * 128 * 2;
  unsigned short* W1B = (unsigned short*)p;   p += (size_t)512 * 128 * 2;
  unsigned short* W2B = (unsigned short*)p;   p += (size_t)64 * 512 * 2;

  k_init<<<256, 256, 0, stream>>>(Wm1, Wm2, (uint4*)eid, W1B, W2B);
  k_xy_mfma<<<NE / 64, 256, 0, stream>>>(C, W1, W2, ei, eid, eidT, X, Y, tmpB);
  k_spmm<<<(NE * 64) / 256, 256, 0, stream>>>(ei, eid, eidT, X, Y, tmpB);
  k_mlp2<<<NE / 32, 256, 0, stream>>>(tmpB, W1B, W2B, out);
}

// Round 5
// 98.258 us; speedup vs baseline: 1.8856x; 1.0104x over previous
//
#include <hip/hip_runtime.h>

#define NN 512
#define NE 16384
#define NF 64

typedef __attribute__((ext_vector_type(8))) short short8_t;
typedef __attribute__((ext_vector_type(4))) float float4_t;

__device__ inline unsigned short f2bf(float f) {
  unsigned u = __builtin_bit_cast(unsigned, f);
  u += 0x7fff + ((u >> 16) & 1);  // round-to-nearest-even (finite inputs)
  return (unsigned short)(u >> 16);
}
__device__ inline float bf2f(unsigned short u) {
  unsigned v = ((unsigned)u) << 16;
  return __builtin_bit_cast(float, v);
}

// ---------------------------------------------------------------------------
// K1: clear presence bitmasks (64 KB; the 2 MB id tables need NO clear — they
// are only read at set-bit positions) + convert W_mlp1/W_mlp2 to bf16.
// Grid: 128 x 256 = 32768 threads.
// ---------------------------------------------------------------------------
__global__ __launch_bounds__(256) void k_init(const float* __restrict__ Wm1,
                                              const float* __restrict__ Wm2,
                                              unsigned* __restrict__ masks,  // 16384 dw
                                              unsigned short* __restrict__ W1B,
                                              unsigned short* __restrict__ W2B) {
  int t = blockIdx.x * 256 + threadIdx.x;
  if (t < 16384) {
    masks[t] = 0u;
    float4 v = ((const float4*)Wm1)[t];
    short4 s;
    s.x = f2bf(v.x); s.y = f2bf(v.y); s.z = f2bf(v.z); s.w = f2bf(v.w);
    ((short4*)W1B)[t] = s;
  } else if (t < 24576) {
    int i = t - 16384;
    float4 v = ((const float4*)Wm2)[i];
    short4 s;
    s.x = f2bf(v.x); s.y = f2bf(v.y); s.z = f2bf(v.z); s.w = f2bf(v.w);
    ((short4*)W2B)[i] = s;
  }
}

// ---------------------------------------------------------------------------
// K2: X = C@W_L1^T, Y = C@W_L2^T via bf16 MFMA (bf16 out now), fused with
// C -> bf16 tmpB[:,0:64] conversion AND edge scatter (ids + presence bits).
// Block = 4 waves x 16 edges.
// ---------------------------------------------------------------------------
__global__ __launch_bounds__(256) void k_xy_mfma(const float* __restrict__ C,
                                                 const float* __restrict__ W1,
                                                 const float* __restrict__ W2,
                                                 const int* __restrict__ ei,
                                                 int* __restrict__ eid,
                                                 int* __restrict__ eidT,
                                                 unsigned* __restrict__ maskO,
                                                 unsigned* __restrict__ maskI,
                                                 unsigned short* __restrict__ Xb,
                                                 unsigned short* __restrict__ Yb,
                                                 unsigned short* __restrict__ tmpB) {
  __shared__ __attribute__((aligned(16))) short W1s[64 * 72];
  __shared__ __attribute__((aligned(16))) short W2s[64 * 72];
  int t = threadIdx.x;
  int w = t >> 6;
  int lane = t & 63;
  int col = lane & 15;
  int q = lane >> 4;
  int base_e = blockIdx.x * 64 + w * 16;

  // scatter this block's 64 edges: id tables + presence bits
  if (t < 64) {
    int e = blockIdx.x * 64 + t;
    int i = ei[e];
    int k = ei[NE + e];
    eid[i * NN + k] = e;
    eidT[k * NN + i] = e;
    atomicOr(&maskO[i * 16 + (k >> 5)], 1u << (k & 31));
    atomicOr(&maskI[k * 16 + (i >> 5)], 1u << (i & 31));
  }

  // stage W1,W2 (fp32 global -> bf16 LDS), 64 rows x 16 float4 granules
#pragma unroll
  for (int z = 0; z < 4; z++) {
    int gi = z * 256 + t;
    int r = gi >> 4, c = gi & 15;
    float4 v1 = ((const float4*)W1)[r * 16 + c];
    float4 v2 = ((const float4*)W2)[r * 16 + c];
    short4 s1, s2;
    s1.x = f2bf(v1.x); s1.y = f2bf(v1.y); s1.z = f2bf(v1.z); s1.w = f2bf(v1.w);
    s2.x = f2bf(v2.x); s2.y = f2bf(v2.y); s2.z = f2bf(v2.z); s2.w = f2bf(v2.w);
    *(short4*)(W1s + r * 72 + c * 4) = s1;
    *(short4*)(W2s + r * 72 + c * 4) = s2;
  }
  __syncthreads();

  // load C rows (fp32), convert, write tmpB, keep as B-fragments
  short8_t bfrag[2];
#pragma unroll
  for (int ks = 0; ks < 2; ks++) {
    float4 c0 = ((const float4*)C)[(size_t)(base_e + col) * 16 + ks * 8 + q * 2];
    float4 c1 = ((const float4*)C)[(size_t)(base_e + col) * 16 + ks * 8 + q * 2 + 1];
    short8_t s;
    s[0] = (short)f2bf(c0.x); s[1] = (short)f2bf(c0.y);
    s[2] = (short)f2bf(c0.z); s[3] = (short)f2bf(c0.w);
    s[4] = (short)f2bf(c1.x); s[5] = (short)f2bf(c1.y);
    s[6] = (short)f2bf(c1.z); s[7] = (short)f2bf(c1.w);
    bfrag[ks] = s;
    *(short8_t*)(tmpB + (size_t)(base_e + col) * 128 + ks * 32 + q * 8) = s;
  }

  float4_t xa[4], ya[4];
#pragma unroll
  for (int ft = 0; ft < 4; ft++) {
    xa[ft] = (float4_t){0.f, 0.f, 0.f, 0.f};
    ya[ft] = (float4_t){0.f, 0.f, 0.f, 0.f};
  }
#pragma unroll
  for (int ks = 0; ks < 2; ks++) {
#pragma unroll
    for (int ft = 0; ft < 4; ft++) {
      short8_t a1 = *(const short8_t*)(W1s + (ft * 16 + col) * 72 + ks * 32 + q * 8);
      short8_t a2 = *(const short8_t*)(W2s + (ft * 16 + col) * 72 + ks * 32 + q * 8);
      xa[ft] = __builtin_amdgcn_mfma_f32_16x16x32_bf16(a1, bfrag[ks], xa[ft], 0, 0, 0);
      ya[ft] = __builtin_amdgcn_mfma_f32_16x16x32_bf16(a2, bfrag[ks], ya[ft], 0, 0, 0);
    }
  }
  // D[row=q*4+r -> f][col -> edge]; store bf16 short4 (halves write traffic)
#pragma unroll
  for (int ft = 0; ft < 4; ft++) {
    short4 sx, sy;
    sx.x = (short)f2bf(xa[ft][0]); sx.y = (short)f2bf(xa[ft][1]);
    sx.z = (short)f2bf(xa[ft][2]); sx.w = (short)f2bf(xa[ft][3]);
    sy.x = (short)f2bf(ya[ft][0]); sy.y = (short)f2bf(ya[ft][1]);
    sy.z = (short)f2bf(ya[ft][2]); sy.w = (short)f2bf(ya[ft][3]);
    *(short4*)(Xb + (size_t)(base_e + col) * 64 + ft * 16 + q * 4) = sx;
    *(short4*)(Yb + (size_t)(base_e + col) * 64 + ft * 16 + q * 4) = sy;
  }
}

// ---------------------------------------------------------------------------
// K3: sparse product via bitmask intersection.  For edge (i,k): AND the 512-bit
// out-mask of i with the in-mask of k (16 lanes x 1 dword), walk the ~2 set
// bits, broadcast-gather the two edge ids, wave-wide feature FMA on bf16 X/Y.
// Traffic/edge ~0.5 KB (was 4 KB dense scan).
// ---------------------------------------------------------------------------
__global__ __launch_bounds__(256) void k_spmm(const int* __restrict__ ei,
                                              const int* __restrict__ eid,
                                              const int* __restrict__ eidT,
                                              const unsigned* __restrict__ maskO,
                                              const unsigned* __restrict__ maskI,
                                              const unsigned short* __restrict__ Xb,
                                              const unsigned short* __restrict__ Yb,
                                              unsigned short* __restrict__ tmpB) {
  int lane = threadIdx.x & 63;
  int e = (blockIdx.x * 256 + threadIdx.x) >> 6;  // one wave per edge
  int i = ei[e];
  int k = ei[NE + e];
  unsigned mm = 0;
  if (lane < 16) mm = maskO[i * 16 + lane] & maskI[k * 16 + lane];
  unsigned long long has = __ballot(mm != 0);
  float acc = 0.f;
  while (has) {
    int l = (int)__builtin_ctzll(has);
    has &= has - 1;
    unsigned bits = __shfl(mm, l);
    while (bits) {
      int b = __builtin_ctz(bits);
      bits &= bits - 1;
      int j = l * 32 + b;
      int s1 = eid[i * NN + j];   // uniform address -> broadcast load
      int s2 = eidT[k * NN + j];
      float xv = bf2f(Xb[(size_t)s1 * 64 + lane]);
      float yv = bf2f(Yb[(size_t)s2 * 64 + lane]);
      acc = fmaf(xv, yv, acc);
    }
  }
  tmpB[(size_t)e * 128 + 64 + lane] = f2bf(acc);
}

// ---------------------------------------------------------------------------
// K4: fused MLP on MFMA, hidden-split for occupancy (unchanged from R3).
// Block = 4 waves = 2 edge-groups x 2 hidden-halves; 512 blocks -> 8 waves/CU.
// ---------------------------------------------------------------------------
__global__ __launch_bounds__(256) void k_mlp2(
    const unsigned short* __restrict__ tmpB,  // [NE][128]
    const unsigned short* __restrict__ W1B,   // [512][128]
    const unsigned short* __restrict__ W2B,   // [64][512]
    float* __restrict__ out) {                // [NE][64]
  __shared__ __attribute__((aligned(16))) short W1s[128 * 136];  // 34816 B
  __shared__ __attribute__((aligned(16))) short W2s[64 * 136];   // 17408 B
  __shared__ __attribute__((aligned(16))) short hS[4][16 * 72];  //  9216 B

  int t = threadIdx.x;
  int w = t >> 6;
  int lane = t & 63;
  int col = lane & 15;
  int q = lane >> 4;
  int g = w & 1;
  int h = w >> 1;
  int base_e = blockIdx.x * 32 + g * 16;

  short8_t btmp[4];
#pragma unroll
  for (int ks = 0; ks < 4; ks++)
    btmp[ks] = *(const short8_t*)(tmpB + (size_t)(base_e + col) * 128 + ks * 32 + q * 8);

  float4_t oacc[4];
#pragma unroll
  for (int ft = 0; ft < 4; ft++) oacc[ft] = (float4_t){0.f, 0.f, 0.f, 0.f};

  for (int it = 0; it < 4; it++) {
    __syncthreads();
    {  // stage W1 chunks (it) and (4+it): 128 rows x 16 uint4
      uint4* d1 = (uint4*)W1s;
      const uint4* s1 = (const uint4*)W1B;
#pragma unroll
      for (int z = 0; z < 8; z++) {
        int gi = z * 256 + t;
        int r = gi >> 4, c = gi & 15;
        int grow = ((r >> 6) * 4 + it) * 64 + (r & 63);
        d1[r * 17 + c] = s1[(size_t)grow * 16 + c];
      }
      uint4* d2 = (uint4*)W2s;
      const uint4* s2 = (const uint4*)W2B;
#pragma unroll
      for (int z = 0; z < 4; z++) {
        int gi = z * 256 + t;
        int r = gi >> 4, c = gi & 15;
        int gc = ((c >> 3) * 4 + it) * 8 + (c & 7);
        d2[r * 17 + c] = s2[(size_t)r * 64 + gc];
      }
    }
    __syncthreads();

    // GEMM1: hT[hid][edge] for this half's 64-hid chunk
#pragma unroll
    for (int ht = 0; ht < 4; ht++) {
      float4_t hacc = (float4_t){0.f, 0.f, 0.f, 0.f};
#pragma unroll
      for (int ks = 0; ks < 4; ks++) {
        short8_t af = *(const short8_t*)(W1s + (h * 64 + ht * 16 + col) * 136 + ks * 32 + q * 8);
        hacc = __builtin_amdgcn_mfma_f32_16x16x32_bf16(af, btmp[ks], hacc, 0, 0, 0);
      }
      short4 hp;
      hp.x = (short)f2bf(fmaxf(hacc[0], 0.f));
      hp.y = (short)f2bf(fmaxf(hacc[1], 0.f));
      hp.z = (short)f2bf(fmaxf(hacc[2], 0.f));
      hp.w = (short)f2bf(fmaxf(hacc[3], 0.f));
      *(short4*)(&hS[w][col * 72 + ht * 16 + q * 4]) = hp;
    }

    // GEMM2: oacc += relu(h) @ W2^T over this half's chunk
#pragma unroll
    for (int ks2 = 0; ks2 < 2; ks2++) {
      short8_t a2 = *(const short8_t*)(&hS[w][col * 72 + ks2 * 32 + q * 8]);
#pragma unroll
      for (int ft = 0; ft < 4; ft++) {
        short8_t b2 = *(const short8_t*)(W2s + (ft * 16 + col) * 136 + h * 64 + ks2 * 32 + q * 8);
        oacc[ft] = __builtin_amdgcn_mfma_f32_16x16x32_bf16(a2, b2, oacc[ft], 0, 0, 0);
      }
    }
  }

  __syncthreads();
  float* red = (float*)W1s;  // [32 edges][stride 66] fp32
  if (h == 1) {
#pragma unroll
    for (int ft = 0; ft < 4; ft++)
#pragma unroll
      for (int r = 0; r < 4; r++)
        red[(g * 16 + q * 4 + r) * 66 + ft * 16 + col] = oacc[ft][r];
  }
  __syncthreads();
  if (h == 0) {
#pragma unroll
    for (int ft = 0; ft < 4; ft++)
#pragma unroll
      for (int r = 0; r < 4; r++) {
        float v = oacc[ft][r] + red[(g * 16 + q * 4 + r) * 66 + ft * 16 + col];
        out[(size_t)(base_e + q * 4 + r) * 64 + ft * 16 + col] = v;
      }
  }
}

// ---------------------------------------------------------------------------
extern "C" void kernel_launch(void* const* d_in, const int* in_sizes, int n_in,
                              void* d_out, int out_size, void* d_ws, size_t ws_size,
                              hipStream_t stream) {
  const int* ei = (const int*)d_in[0];       // [2, E]
  const float* C = (const float*)d_in[1];    // [E, 64]
  const float* W1 = (const float*)d_in[3];   // [64, 64]
  const float* W2 = (const float*)d_in[4];   // [64, 64]
  const float* Wm1 = (const float*)d_in[5];  // [512, 128]
  const float* Wm2 = (const float*)d_in[6];  // [64, 512]
  float* out = (float*)d_out;                // [E, 64]

  char* p = (char*)d_ws;
  int* eid = (int*)p;                 p += (size_t)NN * NN * 4;
  int* eidT = (int*)p;                p += (size_t)NN * NN * 4;
  unsigned* masks = (unsigned*)p;     p += (size_t)16384 * 4;  // maskO|maskI
  unsigned short* Xb = (unsigned short*)p;    p += (size_t)NE * NF * 2;
  unsigned short* Yb = (unsigned short*)p;    p += (size_t)NE * NF * 2;
  unsigned short* tmpB = (unsigned short*)p;  p += (size_t)NE * 128 * 2;
  unsigned short* W1B = (unsigned short*)p;   p += (size_t)512 * 128 * 2;
  unsigned short* W2B = (unsigned short*)p;   p += (size_t)64 * 512 * 2;
  unsigned* maskO = masks;
  unsigned* maskI = masks + 8192;

  k_init<<<128, 256, 0, stream>>>(Wm1, Wm2, masks, W1B, W2B);
  k_xy_mfma<<<NE / 64, 256, 0, stream>>>(C, W1, W2, ei, eid, eidT, maskO, maskI, Xb, Yb, tmpB);
  k_spmm<<<(NE * 64) / 256, 256, 0, stream>>>(ei, eid, eidT, maskO, maskI, Xb, Yb, tmpB);
  k_mlp2<<<NE / 32, 256, 0, stream>>>(tmpB, W1B, W2B, out);
}